// Round 4
// baseline (85.437 us; speedup 1.0000x reference)
//
#include <hip/hip_runtime.h>

// AllPoleDigitalFilter via overlap-and-discard.
// R17: the R13..R16 deltas fit kernel = Fixed(~29us) + 19ns/sample =>
// the inner loop is at the issue floor; the fixed cost is ADDRESS
// DIVERGENCE: every lane owns a chunk 160B from its neighbor, so every
// load/store is a 64-cache-line scatter (~50 coeff loads + 60 x loads +
// 20 stores per wave = ~6k line transactions through the TA pipe).
// Also: even/odd-ci lane pairs shared nb -> computed IDENTICAL 240
// samples (2x redundancy).
// Fix:
//  - LCH 40->80: one lane per 80-output chunk (same warm 160, same 240
//    serial samples, bit-identical arithmetic). Waves 800->416.
//  - Cooperative LDS staging, all global traffic coalesced:
//    x: 68 frame-rows padded to 81 floats (bank stride 17, odd ->
//       conflict-free per-lane reads; lane rows are consecutive).
//    coeffs: 68 rows x 25 (stride 25 coprime 32 -> conflict-free gather).
//    outputs: lane -> LDS row 81-padded, then one coalesced block store.
// Inner compute (validated R13..R16, absmax 0.03515625): per-8-group
// midpoint taps, exact per-sample gain, dual-aligned v2f rings
// wA[i]={y[2i],y[2i+1]} / wB[i]={y[2i+1],y[2i+2]} -> v_pk_fma_f32 without
// pair-building movs; packed negated coeffs parity-invariant; taps 1,2
// scalar (1-FMA inter-sample critical path); first-order K*x warm-start.

typedef float v2f __attribute__((ext_vector_type(2)));

#define BATCH 32
#define N_FRAMES 800
#define D_COEF 25
#define P_FRAME 80
#define T_SAMP 64000
#define LCH 80
#define CHUNKS 800               // per batch row
#define NBLK 13                  // ceil(800/64)
#define XROWS 68
#define XPAD 81
#define CROWS 68
#define OPAD 81

// ring slot helpers (all args non-negative; +80 bias removes any doubt)
__device__ __forceinline__ constexpr int slotA(int s)  { return ((s + 80) % 40) / 2; }       // even s: wA[slotA].x=y[s]; odd s uses slotAy
__device__ __forceinline__ constexpr int slotAy(int s) { return ((s + 80 - 1) % 40) / 2; }   // odd s: wA[slotAy].y=y[s]
__device__ __forceinline__ constexpr int slotBx(int s) { return ((s + 80 - 1) % 40) / 2; }   // odd s: wB[slotBx].x=y[s]
__device__ __forceinline__ constexpr int slotBy(int s) { return ((s + 80 - 2) % 40) / 2; }   // even s: wB[slotBy].y=y[s]

__device__ __forceinline__ float4 ld4(const float* p) {
    return make_float4(p[0], p[1], p[2], p[3]);
}

__global__
__attribute__((amdgpu_flat_work_group_size(64, 64)))
__attribute__((amdgpu_waves_per_eu(1, 1)))
void lpc_kernel(const float* __restrict__ x,
                const float* __restrict__ a,
                float* __restrict__ out) {
    __shared__ float xs[XROWS * XPAD];       // x window, row-padded
    __shared__ float cs[CROWS * D_COEF];     // coeff rows
    __shared__ float outs[64 * OPAD];        // per-lane output rows

    const int c0 = blockIdx.x * 64;          // chunk base within batch row
    const int b  = blockIdx.y;
    const float* xrow = x + (size_t)b * T_SAMP;
    float* orow = out + (size_t)b * T_SAMP;
    const float* arow = a + (size_t)b * (N_FRAMES * D_COEF);

    const int nbase = (c0 >= 2) ? c0 - 2 : 0;
    const int row0  = (nbase >= 1) ? nbase - 1 : 0;   // first staged frame-row

    // ---- cooperative coalesced staging ----
    for (int i = threadIdx.x; i < (XROWS * P_FRAME) / 4; i += 64) {   // 1360 float4
        int fi = 4 * i;
        int gi = row0 * P_FRAME + fi;
        if (gi > T_SAMP - 4) gi = T_SAMP - 4;          // tail rows: junk, never consumed
        float4 v = *(const float4*)(xrow + gi);
        int r = fi / P_FRAME;
        int c = fi - r * P_FRAME;
        float* d = xs + r * XPAD + c;
        d[0] = v.x; d[1] = v.y; d[2] = v.z; d[3] = v.w;
    }
    for (int i = threadIdx.x; i < CROWS * D_COEF; i += 64) {
        int r = i / D_COEF;
        int q = i - r * D_COEF;
        int gr = row0 + r; if (gr > N_FRAMES - 1) gr = N_FRAMES - 1;
        cs[i] = arow[gr * D_COEF + q];
    }
    __syncthreads();

    // ---- per-lane setup ----
    const int tid = threadIdx.x;
    const int ci = c0 + tid;                 // may be >=800 in last block: computes
                                             // safely in-range, never stores
    const int s0 = ci * LCH;
    const int nb = (ci >= 2) ? ci - 2 : 0;   // warm 160 for ci>=2; ci<2 exact from t=0
    const int t0 = nb * P_FRAME;
    const int R0 = nb - row0;                // LDS row of frame nb (x and coeff)

    v2f wA[20], wB[20];
#pragma unroll
    for (int i = 0; i < 20; ++i) {
        wA[i].x = 0.0f; wA[i].y = 0.0f;
        wB[i].x = 0.0f; wB[i].y = 0.0f;
    }

    const float inv_p = 1.0f / (float)P_FRAME;

    // First-order refined warm-start (validated R15/R16): ring P=0..23 hold
    // y[t0-24..t0-1]. z window = x[t0-48..t0) = LDS row R0-1 cols 32..79.
    if (nb > 0) {
        const float* cm1 = cs + (R0 - 1) * D_COEF;   // coeff row nb-1
        const float* cc0 = cs + R0 * D_COEF;         // coeff row nb
        const float gm1 = cm1[0];
        const float dg = (cc0[0] - gm1) * inv_p;

        float z[48];
        const float* zr = xs + (R0 - 1) * XPAD + 32;
#pragma unroll
        for (int i = 0; i < 48; ++i) z[i] = zr[i];
#pragma unroll
        for (int i = 0; i < 48; ++i) {
            float Kv = fmaf(dg, (float)(32 + i), gm1);
            z[i] *= Kv;
        }
        float am[24];
#pragma unroll
        for (int m = 0; m < 24; ++m) {
            float cc = cm1[1 + m];
            am[m] = fmaf(cc0[1 + m] - cc, 0.7f, cc);
        }
#pragma unroll
        for (int i = 0; i < 24; ++i) {
            float s = z[24 + i];
#pragma unroll
            for (int m = 1; m <= 24; ++m) s = fmaf(-am[m - 1], z[24 + i - m], s);
            if (i & 1) { wA[slotAy(i)].y = s; wB[slotBx(i)].x = s; }
            else       { wA[slotA(i)].x  = s; wB[slotBy(i)].y = s; }
        }
    }

    // initial x regs: frame-0 row, cols 0..15
    {
        // nothing
    }
    const float* xr0 = xs + R0 * XPAD;
    float4 xc0 = ld4(xr0);
    float4 xc1 = ld4(xr0 + 4);
    float4 xn0 = ld4(xr0 + 8);
    float4 xn1 = ld4(xr0 + 12);

#pragma unroll 1
    for (int f = 0; f < 3; ++f) {            // 3 frames: warm 160 + 80 out
        int n = nb + f;  if (n > N_FRAMES - 1) n = N_FRAMES - 1;
        int n1 = n + 1;  if (n1 > N_FRAMES - 1) n1 = N_FRAMES - 1;
        const float* r0 = cs + (n - row0) * D_COEF;
        const float* r1 = cs + (n1 - row0) * D_COEF;

        float g0 = r0[0];
        float dk = (r1[0] - g0) * inv_p;
        float k = g0;

        float nc1, nc2, dn1, dn2;
        {
            float c1 = r0[1], c2 = r0[2];
            float d1 = (r1[1] - c1) * inv_p;
            float d2 = (r1[2] - c2) * inv_p;
            nc1 = -fmaf(d1, 3.5f, c1);  dn1 = -8.0f * d1;
            nc2 = -fmaf(d2, 3.5f, c2);  dn2 = -8.0f * d2;
        }
        v2f cp[11], d8[11];
#pragma unroll
        for (int r = 0; r < 11; ++r) {
            float cLo = r0[4 + 2 * r], cHi = r0[3 + 2 * r];
            float dLo = (r1[4 + 2 * r] - cLo) * inv_p;
            float dHi = (r1[3 + 2 * r] - cHi) * inv_p;
            cp[r].x = -fmaf(dLo, 3.5f, cLo);
            cp[r].y = -fmaf(dHi, 3.5f, cHi);
            d8[r].x = -8.0f * dLo;
            d8[r].y = -8.0f * dHi;
        }

        const int fr = R0 + f;               // x LDS row of this frame

#pragma unroll
        for (int gg = 0; gg < 10; ++gg) {
            // prefetch group gg+2 (consumed 2 groups later; f=2 gg>=8 never consumed,
            // rows stay < XROWS by construction: fr+1 <= R0+3 <= 67)
            const int tpl = gg * 8 + 16;
            const int prow = fr + ((tpl >= 80) ? 1 : 0);
            const int pcol = (tpl >= 80) ? (tpl - 80) : tpl;
            const float* pp = xs + prow * XPAD + pcol;
            float4 xf0 = ld4(pp);
            float4 xf1 = ld4(pp + 4);

#pragma unroll
            for (int j = 0; j < 8; ++j) {
                const int P = 24 + gg * 8 + j;        // compile-time ring pos
                float xv = (j == 0) ? xc0.x : (j == 1) ? xc0.y
                         : (j == 2) ? xc0.z : (j == 3) ? xc0.w
                         : (j == 4) ? xc1.x : (j == 5) ? xc1.y
                         : (j == 6) ? xc1.z : xc1.w;
                float e = k * xv;

                // taps 3..24: 11 pk ops, 3 chains; pair r covers lags 3+2r,4+2r
                v2f A, B, C;
#pragma unroll
                for (int r = 0; r < 11; ++r) {
                    v2f pr = (P & 1) ? wB[slotBx(P - 3 - 2 * r)]
                                     : wA[slotA(P - 4 - 2 * r)];
                    if (r == 0)          A = cp[r] * pr;
                    else if (r == 1)     B = cp[r] * pr;
                    else if (r == 2)     C = cp[r] * pr;
                    else if (r % 3 == 0) A += cp[r] * pr;
                    else if (r % 3 == 1) B += cp[r] * pr;
                    else                 C += cp[r] * pr;
                }
                v2f S = (A + B) + C;
                float t1 = e + (S.x + S.y);
                float ym1 = (P & 1) ? wA[slotA(P - 1)].x  : wA[slotAy(P - 1)].y;  // y[P-1]
                float ym2 = (P & 1) ? wA[slotAy(P - 2)].y : wA[slotA(P - 2)].x;   // y[P-2]
                float u = fmaf(nc2, ym2, t1);
                float y = fmaf(nc1, ym1, u);

                if (P & 1) {
                    wA[slotAy(P)].y = y;
                    wB[slotBx(P)].x = y;
                } else {
                    wA[slotA(P)].x = y;
                    wB[slotBy(P)].y = y;
                }
                k += dk;
            }

            const int tg = t0 + f * P_FRAME + gg * 8;
            if ((unsigned)(tg - s0) < (unsigned)LCH) {    // ci>=800: never true
                const int Q = 24 + gg * 8;                // even -> pairs from wA
                float* od = outs + tid * OPAD + (tg - s0);
                od[0] = wA[slotA(Q + 0)].x; od[1] = wA[slotA(Q + 0)].y;
                od[2] = wA[slotA(Q + 2)].x; od[3] = wA[slotA(Q + 2)].y;
                od[4] = wA[slotA(Q + 4)].x; od[5] = wA[slotA(Q + 4)].y;
                od[6] = wA[slotA(Q + 6)].x; od[7] = wA[slotA(Q + 6)].y;
            }
            if (gg < 9) {
                nc1 += dn1; nc2 += dn2;
#pragma unroll
                for (int r = 0; r < 11; ++r) cp[r] += d8[r];   // v_pk_add_f32
            }
            xc0 = xn0; xc1 = xn1;                     // rotate at group END
            xn0 = xf0; xn1 = xf1;
        }
    }

    __syncthreads();

    // ---- coalesced block store ----
    int nact = CHUNKS - c0; if (nact > 64) nact = 64;   // active chunks this block
    const int total4 = nact * LCH / 4;
    for (int i = threadIdx.x; i < total4; i += 64) {
        int fi = 4 * i;
        int r = fi / LCH;
        int c = fi - r * LCH;
        const float* sp = outs + r * OPAD + c;
        *(float4*)(orow + (size_t)c0 * LCH + fi) = make_float4(sp[0], sp[1], sp[2], sp[3]);
    }
}

extern "C" void kernel_launch(void* const* d_in, const int* in_sizes, int n_in,
                              void* d_out, int out_size, void* d_ws, size_t ws_size,
                              hipStream_t stream) {
    const float* x = (const float*)d_in[0];
    const float* a = (const float*)d_in[1];
    float* out = (float*)d_out;

    dim3 block(64);
    dim3 grid(NBLK, BATCH);                  // 13 x 32 = 416 one-wave blocks
    hipLaunchKernelGGL(lpc_kernel, grid, block, 0, stream, x, a, out);
}

// Round 5
// 77.127 us; speedup vs baseline: 1.1077x; 1.1077x over previous
//
#include <hip/hip_runtime.h>

// AllPoleDigitalFilter via overlap-and-discard.
// R18: I-CACHE theory. R17 refuted address-divergence as the fixed cost
// (removing it regressed 33->44us/wave). Remaining explanation for the
// ~25us fixed per-wave component and ~12-15 cyc/instr effective rate:
// 240 fully-unrolled samples = ~46KB straight-line code > I-cache; every
// wave streams its text from L2. R17 made it worse by adding code and
// halving co-resident waves.
// Fix: ring period 40 = 5 groups, and frames advance 80 = 0 (mod 40), so
// groups 0-4 / 5-9 / all frames share ONE slot pattern. Roll 30 groups
// into 6 iterations x 5-group unrolled body (~10KB, I-cache-hot after
// iter 1). Frame setup under uniform (it&1)==0 branch. All register-array
// indices remain compile-time (no scratch). Consumed arithmetic is
// bit-identical to R16 (absmax 0.03515625): same ops, same order; only a
// dead cp-advance after each frame's last group added.
// Base config = R16 (known 33us/wave): LCH=40, CHUNKS=1600, 800 one-wave
// blocks, waves_per_eu(1,1), global loads, coeff double-buffer
// ccur/cnxt/cfut, first-order K*x warm-start (warm 160/200).

typedef float v2f __attribute__((ext_vector_type(2)));

#define BATCH 32
#define N_FRAMES 800
#define D_COEF 25
#define P_FRAME 80
#define T_SAMP 64000
#define LCH 40
#define CHUNKS 1600              // per batch row

// ring slot helpers (all args non-negative; +80 bias removes any doubt)
__device__ __forceinline__ constexpr int slotA(int s)  { return ((s + 80) % 40) / 2; }       // even s: wA[slotA].x=y[s]; odd s uses slotAy
__device__ __forceinline__ constexpr int slotAy(int s) { return ((s + 80 - 1) % 40) / 2; }   // odd s: wA[slotAy].y=y[s]
__device__ __forceinline__ constexpr int slotBx(int s) { return ((s + 80 - 1) % 40) / 2; }   // odd s: wB[slotBx].x=y[s]
__device__ __forceinline__ constexpr int slotBy(int s) { return ((s + 80 - 2) % 40) / 2; }   // even s: wB[slotBy].y=y[s]

__global__
__attribute__((amdgpu_flat_work_group_size(64, 64)))
__attribute__((amdgpu_waves_per_eu(1, 1)))
void lpc_kernel(const float* __restrict__ x,
                const float* __restrict__ a,
                float* __restrict__ out) {
    const int g = blockIdx.x * 64 + threadIdx.x;
    const int b = g / CHUNKS;
    const int ci = g - b * CHUNKS;
    const int s0 = ci * LCH;
    const int nb = (ci >= 4) ? ((ci - 4) >> 1) : 0;   // warm 160 (even ci) / 200 (odd ci); ci<4 exact from t=0
    const int t0 = nb * P_FRAME;

    const float* xrow = x + (size_t)b * T_SAMP;
    float* orow = out + (size_t)b * T_SAMP;
    const float* arow = a + (size_t)b * (N_FRAMES * D_COEF);

    v2f wA[20], wB[20];
#pragma unroll
    for (int i = 0; i < 20; ++i) {
        wA[i].x = 0.0f; wA[i].y = 0.0f;
        wB[i].x = 0.0f; wB[i].y = 0.0f;
    }

    const float inv_p = 1.0f / (float)P_FRAME;

    // Coefficient register double-buffer: ccur = frame nb, cnxt = frame nb+1.
    float ccur[D_COEF], cnxt[D_COEF], cfut[D_COEF];
    {
        const float* rc = arow + nb * D_COEF;
        const int n1i = (nb + 1 < N_FRAMES) ? nb + 1 : N_FRAMES - 1;
        const float* rn = arow + n1i * D_COEF;
#pragma unroll
        for (int q = 0; q < D_COEF; ++q) { ccur[q] = rc[q]; cnxt[q] = rn[q]; }
    }

    // First-order refined warm-start (validated R15/R16): ring positions
    // P=0..23 hold y[t0-24 .. t0-1]. Samples t0-48+i sit at p=32+i of
    // frame nb-1. z[i] = K(t)*x(t); y0[i] = z[24+i] - sum_m am[m]*z[24+i-m]
    // (taps interpolated at the history midpoint p~56 -> frac 0.7).
    if (nb > 0) {
        const float* rm1 = arow + (nb - 1) * D_COEF;
        const float gm1 = rm1[0];
        const float dg = (ccur[0] - gm1) * inv_p;

        float z[48];
#pragma unroll
        for (int q = 0; q < 12; ++q) {
            float4 xq = *(const float4*)(xrow + t0 - 48 + 4 * q);
            z[4 * q + 0] = xq.x; z[4 * q + 1] = xq.y;
            z[4 * q + 2] = xq.z; z[4 * q + 3] = xq.w;
        }
#pragma unroll
        for (int i = 0; i < 48; ++i) {
            float Kv = fmaf(dg, (float)(32 + i), gm1);
            z[i] *= Kv;
        }
        float am[24];
#pragma unroll
        for (int m = 0; m < 24; ++m) {
            float c0 = rm1[1 + m];
            am[m] = fmaf(ccur[1 + m] - c0, 0.7f, c0);
        }
#pragma unroll
        for (int i = 0; i < 24; ++i) {
            float s = z[24 + i];
#pragma unroll
            for (int m = 1; m <= 24; ++m) s = fmaf(-am[m - 1], z[24 + i - m], s);
            if (i & 1) { wA[slotAy(i)].y = s; wB[slotBx(i)].x = s; }
            else       { wA[slotA(i)].x  = s; wB[slotBy(i)].y = s; }
        }
    }

    float4 xc0 = *(const float4*)(xrow + t0);
    float4 xc1 = *(const float4*)(xrow + t0 + 4);
    float4 xn0 = *(const float4*)(xrow + t0 + 8);
    float4 xn1 = *(const float4*)(xrow + t0 + 12);

    float k = 0.0f, dk = 0.0f, nc1 = 0.0f, nc2 = 0.0f, dn1 = 0.0f, dn2 = 0.0f;
    v2f cp[11], d8[11];
#pragma unroll
    for (int r = 0; r < 11; ++r) { cp[r].x = 0.0f; cp[r].y = 0.0f; d8[r].x = 0.0f; d8[r].y = 0.0f; }

    // 6 iterations x 5 groups = 30 groups = 3 frames (ring pattern period
    // is exactly 5 groups; frames advance 0 mod 40).
#pragma unroll 1
    for (int it = 0; it < 6; ++it) {
        if ((it & 1) == 0) {
            // frame setup from resident registers (uniform branch)
            float g0 = ccur[0];
            dk = (cnxt[0] - g0) * inv_p;
            k = g0;
            {
                float c1 = ccur[1], c2 = ccur[2];
                float d1 = (cnxt[1] - c1) * inv_p;
                float d2 = (cnxt[2] - c2) * inv_p;
                nc1 = -fmaf(d1, 3.5f, c1);  dn1 = -8.0f * d1;
                nc2 = -fmaf(d2, 3.5f, c2);  dn2 = -8.0f * d2;
            }
#pragma unroll
            for (int r = 0; r < 11; ++r) {
                float cLo = ccur[4 + 2 * r], cHi = ccur[3 + 2 * r];
                float dLo = (cnxt[4 + 2 * r] - cLo) * inv_p;
                float dHi = (cnxt[3 + 2 * r] - cHi) * inv_p;
                cp[r].x = -fmaf(dLo, 3.5f, cLo);
                cp[r].y = -fmaf(dHi, 3.5f, cHi);
                d8[r].x = -8.0f * dLo;
                d8[r].y = -8.0f * dHi;
            }
            // prefetch frame f+2's coefficient row (hidden under 2 iterations)
            if (it < 4) {
                const int n2c = (nb + (it >> 1) + 2 < N_FRAMES) ? nb + (it >> 1) + 2 : N_FRAMES - 1;
                const float* r2 = arow + n2c * D_COEF;
#pragma unroll
                for (int q = 0; q < D_COEF; ++q) cfut[q] = r2[q];
            }
        }

#pragma unroll
        for (int gi = 0; gi < 5; ++gi) {
            const int tg = t0 + it * 40 + gi * 8;     // runtime (it), uniform shape
            int tp = tg + 16; if (tp > T_SAMP - 8) tp = T_SAMP - 8;
            float4 xf0 = *(const float4*)(xrow + tp);
            float4 xf1 = *(const float4*)(xrow + tp + 4);

#pragma unroll
            for (int j = 0; j < 8; ++j) {
                const int P = 24 + gi * 8 + j;        // compile-time ring pos (mod-40 pattern)
                float xv = (j == 0) ? xc0.x : (j == 1) ? xc0.y
                         : (j == 2) ? xc0.z : (j == 3) ? xc0.w
                         : (j == 4) ? xc1.x : (j == 5) ? xc1.y
                         : (j == 6) ? xc1.z : xc1.w;
                float e = k * xv;

                // taps 3..24: 11 pk ops, 3 chains; pair r covers lags 3+2r,4+2r
                v2f A, B, C;
#pragma unroll
                for (int r = 0; r < 11; ++r) {
                    v2f pr = (P & 1) ? wB[slotBx(P - 3 - 2 * r)]
                                     : wA[slotA(P - 4 - 2 * r)];
                    if (r == 0)          A = cp[r] * pr;
                    else if (r == 1)     B = cp[r] * pr;
                    else if (r == 2)     C = cp[r] * pr;
                    else if (r % 3 == 0) A += cp[r] * pr;
                    else if (r % 3 == 1) B += cp[r] * pr;
                    else                 C += cp[r] * pr;
                }
                v2f S = (A + B) + C;
                float t1 = e + (S.x + S.y);
                float ym1 = (P & 1) ? wA[slotA(P - 1)].x  : wA[slotAy(P - 1)].y;  // y[P-1]
                float ym2 = (P & 1) ? wA[slotAy(P - 2)].y : wA[slotA(P - 2)].x;   // y[P-2]
                float u = fmaf(nc2, ym2, t1);
                float y = fmaf(nc1, ym1, u);

                // mirror write into both rings
                if (P & 1) {
                    wA[slotAy(P)].y = y;
                    wB[slotBx(P)].x = y;
                } else {
                    wA[slotA(P)].x = y;
                    wB[slotBy(P)].y = y;
                }
                k += dk;
            }

            if ((unsigned)(tg - s0) < 40u) {          // tg, s0 multiples of 8
                const int Q = 24 + gi * 8;            // even -> pairs from wA
                *(float4*)(orow + tg)     = make_float4(wA[slotA(Q + 0)].x, wA[slotA(Q + 0)].y,
                                                        wA[slotA(Q + 2)].x, wA[slotA(Q + 2)].y);
                *(float4*)(orow + tg + 4) = make_float4(wA[slotA(Q + 4)].x, wA[slotA(Q + 4)].y,
                                                        wA[slotA(Q + 6)].x, wA[slotA(Q + 6)].y);
            }

            // per-group advance (last advance of a frame is dead: frame
            // setup recomputes before next consumption -> bit-identical)
            nc1 += dn1; nc2 += dn2;
#pragma unroll
            for (int r = 0; r < 11; ++r) cp[r] += d8[r];   // v_pk_add_f32
            xc0 = xn0; xc1 = xn1;                     // rotate at group END
            xn0 = xf0; xn1 = xf1;
        }

        // rotate coefficient buffers at frame end (register movs)
        if ((it & 1) == 1 && it < 5) {
#pragma unroll
            for (int q = 0; q < D_COEF; ++q) { ccur[q] = cnxt[q]; cnxt[q] = cfut[q]; }
        }
    }
}

extern "C" void kernel_launch(void* const* d_in, const int* in_sizes, int n_in,
                              void* d_out, int out_size, void* d_ws, size_t ws_size,
                              hipStream_t stream) {
    const float* x = (const float*)d_in[0];
    const float* a = (const float*)d_in[1];
    float* out = (float*)d_out;

    dim3 block(64);
    dim3 grid(BATCH * CHUNKS / 64);      // 800 one-wave blocks
    hipLaunchKernelGGL(lpc_kernel, grid, block, 0, stream, x, a, out);
}